// Round 1
// baseline (405.164 us; speedup 1.0000x reference)
//
#include <hip/hip_runtime.h>
#include <math.h>

// FieldAwareInteractionLayer: out[b,p,:] = table[X[b,i_p], j_p, :] * table[X[b,j_p], i_p, :]
// F=39, 741 pairs, EMB=16 fp32.
//
// Direct-gather version: the staged-LDS design had zero data reuse (each 64 B
// slice feeds exactly one pair) — LDS bought only coalescing, at the cost of a
// vmcnt-serialized staging loop + 2 barriers + 55 KB LDS (2 blocks/CU).
// Instead: one 512-thread block per sample (keeps the sample's 39 rows hot in
// ONE XCD's L2), a 5.9 KB per-pair base-offset LUT in LDS, then a barrier-free
// fully-unrolled gather loop: 12 independent 16 B loads in flight per thread.
// Left reads stream contiguous row slices; right reads are 64 B-granular
// scatters that stay L2-resident (97 KB/sample << 4 MB). fp32 throughout ->
// products exactly match the reference (absmax = 0).

#define F      39
#define NPAIR  741            // 39*38/2
#define ROWF4  (F * 4)        // 156 float4 per table row
#define OUTF4  (NPAIR * 4)    // 2964 float4 per sample
#define BLK    512
#define NITER  6              // ceil(2964/512); iters 0..4 full, iter 5 partial

typedef float fx4 __attribute__((ext_vector_type(4)));

__global__ __launch_bounds__(BLK, 4) void ffm_direct_kernel(
    const int* __restrict__ X,
    const fx4* __restrict__ table4,   // [100000][156] float4
    fx4*       __restrict__ out4)     // [4096][2964] float4
{
    __shared__ int  xrow[F];
    __shared__ int2 base2[NPAIR];   // {left float4 base, right float4 base}

    const int b   = blockIdx.x;
    const int tid = threadIdx.x;

    if (tid < F) xrow[tid] = X[b * F + tid];
    __syncthreads();

    // Build per-pair base offsets (float4 units). Same decode as before:
    // p -> (i,j), i<j, row-major triu; start(i) = i*(77-i)/2.
    for (int p = tid; p < NPAIR; p += BLK) {
        int i = (int)((77.0f - sqrtf(5929.0f - 8.0f * (float)p)) * 0.5f);
        i = i < 0 ? 0 : (i > 38 ? 38 : i);
        while (((i + 1) * (77 - (i + 1))) / 2 <= p) ++i;
        while ((i * (77 - i)) / 2 > p) --i;
        const int j = p - (i * (77 - i)) / 2 + i + 1;
        base2[p] = make_int2(xrow[i] * ROWF4 + j * 4,    // table[X[b,i], j, :]
                             xrow[j] * ROWF4 + i * 4);   // table[X[b,j], i, :]
    }
    __syncthreads();

    fx4* __restrict__ ob = out4 + (size_t)b * OUTF4;

    // Barrier-free gather/multiply/store. 4 threads per pair (one float4 each).
    // Full unroll: all LDS reads + global loads issue up front -> deep MLP.
    #pragma unroll
    for (int k = 0; k < NITER; ++k) {
        const int o = tid + k * BLK;
        if (k < NITER - 1 || o < OUTF4) {
            const int p = o >> 2;
            const int e = o & 3;
            const int2 ba = base2[p];     // 4 lanes same addr -> LDS broadcast
            const fx4 L = table4[ba.x + e];
            const fx4 R = table4[ba.y + e];
            fx4 v;
            v.x = L.x * R.x;
            v.y = L.y * R.y;
            v.z = L.z * R.z;
            v.w = L.w * R.w;
            __builtin_nontemporal_store(v, ob + o);
        }
    }
}

extern "C" void kernel_launch(void* const* d_in, const int* in_sizes, int n_in,
                              void* d_out, int out_size, void* d_ws, size_t ws_size,
                              hipStream_t stream) {
    const int*   X     = (const int*)d_in[0];
    const float* table = (const float*)d_in[1];
    float*       out   = (float*)d_out;

    const int batch = in_sizes[0] / F;   // 4096

    ffm_direct_kernel<<<dim3(batch), dim3(BLK), 0, stream>>>(
        X, (const fx4*)table, (fx4*)out);
}